// Round 10
// baseline (137.383 us; speedup 1.0000x reference)
//
#include <hip/hip_runtime.h>
#include <cstddef>

// Problem constants
constexpr int Bn  = 16;    // batch
constexpr int CIc = 32;    // in channels
constexpr int COc = 32;    // out channels
constexpr int Kc  = 16;    // kernel width
constexpr int IN  = 8192;  // input length
constexpr int OUTL = 8176; // output length = IN - K

// Tiling — round-2 structure, chunk granularity doubled (4 chunks -> 2)
constexpr int O_B  = 16;   // o-positions per block (8176/16 = 511 exact)
constexpr int CCH  = 16;   // channels staged per chunk (was 8)
constexpr int NPOS = 32;   // staged positions; o0+31 <= 8191 always in bounds
constexpr int BST  = 20;   // padded row stride (reads 2-way + broadcast = free)
constexpr int NCHUNK = CIc / CCH;  // 2

__global__ __launch_bounds__(256, 2)
void conv1d_cppn_kernel(const float* __restrict__ x, const float* __restrict__ w,
                        const float* __restrict__ bias, float* __restrict__ out) {
    // x transposed: xs[cc][pos][b]  (16*32*20*4 = 40,960 B -> under 64KB static cap)
    __shared__ float xs[CCH][NPOS][BST];

    const int tid = threadIdx.x;
    const int og = tid & 15;          // o within tile (fast -> coalesced w loads)
    const int dg = tid >> 4;          // 16 d-groups x 2 d = all 32 d
    const int o0 = blockIdx.x * O_B;
    const int o  = o0 + og;
    const int dbase = dg * 2;

    // Staging decomposition: (sp4, sb), channels cl0 + 2q, q = 0..7
    const int sp4 = tid & 7;
    const int sb  = (tid >> 3) & 15;
    const int cl0 = tid >> 7;

    // ===== round-2-proven register shape: DO NOT ALTER =====
    float acc[2][16];
#pragma unroll
    for (int i = 0; i < 2; ++i)
#pragma unroll
        for (int j = 0; j < 16; ++j) acc[i][j] = 0.f;

    for (int chunk = 0; chunk < NCHUNK; ++chunk) {
        const int c0 = chunk * CCH;
        __syncthreads();
        // Stage x[b, c0..c0+16, o0..o0+32) transposed. 8 float4 loads/thread,
        // all independent; consecutive lanes -> consecutive addresses.
#pragma unroll
        for (int q = 0; q < 8; ++q) {
            const int cl = cl0 + 2 * q;   // 0..15
            const float4 v = *reinterpret_cast<const float4*>(
                &x[((size_t)sb * CIc + (c0 + cl)) * IN + o0 + sp4 * 4]);
            float (*prow)[BST] = &xs[cl][sp4 * 4];
            prow[0][sb] = v.x; prow[1][sb] = v.y; prow[2][sb] = v.z; prow[3][sb] = v.w;
        }
        __syncthreads();

#pragma unroll 2   // round-2 proven: bounded unroll
        for (int cc = 0; cc < CCH; ++cc) {
            const int c = c0 + cc;
            float wreg[2][16];
#pragma unroll
            for (int jd = 0; jd < 2; ++jd) {
                const float4* wp = reinterpret_cast<const float4*>(
                    w + (((size_t)(dbase + jd) * CIc + c) * OUTL + o) * Kc);
#pragma unroll
                for (int q = 0; q < 4; ++q) {
                    const float4 v = wp[q];
                    wreg[jd][q * 4 + 0] = v.x;
                    wreg[jd][q * 4 + 1] = v.y;
                    wreg[jd][q * 4 + 2] = v.z;
                    wreg[jd][q * 4 + 3] = v.w;
                }
            }
#pragma unroll
            for (int k = 0; k < Kc; ++k) {
                const float* xrow = &xs[cc][og + k][0];
                float xv[16];
                *reinterpret_cast<float4*>(&xv[0])  = *reinterpret_cast<const float4*>(xrow);
                *reinterpret_cast<float4*>(&xv[4])  = *reinterpret_cast<const float4*>(xrow + 4);
                *reinterpret_cast<float4*>(&xv[8])  = *reinterpret_cast<const float4*>(xrow + 8);
                *reinterpret_cast<float4*>(&xv[12]) = *reinterpret_cast<const float4*>(xrow + 12);
#pragma unroll
                for (int jd = 0; jd < 2; ++jd) {
                    const float wk = wreg[jd][k];
#pragma unroll
                    for (int jb = 0; jb < 16; ++jb) {
                        acc[jd][jb] += wk * xv[jb];
                    }
                }
            }
        }
    }
    // ===== end protected inner loop =====

    // Epilogue: bias + relu, coalesced over o (consecutive lanes -> consecutive o)
#pragma unroll
    for (int jd = 0; jd < 2; ++jd) {
        const float bv = bias[dbase + jd];
#pragma unroll
        for (int jb = 0; jb < 16; ++jb) {
            float v = acc[jd][jb] + bv;
            out[((size_t)jb * COc + (dbase + jd)) * OUTL + o] = v > 0.f ? v : 0.f;
        }
    }
}

extern "C" void kernel_launch(void* const* d_in, const int* in_sizes, int n_in,
                              void* d_out, int out_size, void* d_ws, size_t ws_size,
                              hipStream_t stream) {
    const float* x    = (const float*)d_in[0];
    const float* w    = (const float*)d_in[1];
    const float* bias = (const float*)d_in[2];
    float* out        = (float*)d_out;

    dim3 grid(OUTL / O_B);  // 511
    dim3 block(256);
    hipLaunchKernelGGL(conv1d_cppn_kernel, grid, block, 0, stream, x, w, bias, out);
}